// Round 8
// baseline (199.808 us; speedup 1.0000x reference)
//
#include <hip/hip_runtime.h>
#include <math.h>

#define BB 32
#define CC 256
#define CQ 32      // C/8
#define NN 1024    // H*W

typedef short bf16x8 __attribute__((ext_vector_type(8)));
typedef float f32x4  __attribute__((ext_vector_type(4)));
typedef unsigned short u16;

// fp32 -> bf16 RNE
__device__ __forceinline__ u16 f2bf(float f) {
    unsigned u = __float_as_uint(f);
    u = (u + 0x7FFFu + ((u >> 16) & 1u)) >> 16;
    return (u16)u;
}

// pack two fp32 -> two bf16 in one u32 (single VALU op)
__device__ __forceinline__ unsigned cvt_pk_bf16(float lo, float hi) {
    unsigned r;
    asm("v_cvt_pk_bf16_f32 %0, %1, %2" : "=v"(r) : "v"(lo), "v"(hi));
    return r;
}

// ---------------------------------------------------------------------------
// Kernel 1: QKV projection. grid(32 n-tiles, 32 b), 256 thr, 4 blocks/CU.
// wpack kernel ELIMINATED: W frags are read directly from global with the
// swizzled access (rows rt*16+c16, 8 consecutive f32) + cvt_pk to bf16.
// W is 320KB -> L2-resident after first touch; costs 20 VALU/k-step, saves
// one kernel launch + the wfrag round-trip. Layouts (qt/kt/vv) standard,
// as the r3 attn expects.
// ---------------------------------------------------------------------------
struct QSmem {
    union {
        u16 xs[32][268];     // x^T tile [n][c] bf16, stride 268 (bank-spread)
        u16 osv[CC][40];     // v result [c][n]
    };
    u16 osqk[32][72];        // q|k result [n][d], d 0..31 = q, 32..63 = k
};

__global__ __launch_bounds__(256, 4) void qkv_kernel(
    const float* __restrict__ x,
    const float* __restrict__ Wq, const float* __restrict__ Wk,
    const float* __restrict__ Wv,
    const float* __restrict__ bq, const float* __restrict__ bk,
    const float* __restrict__ bv,
    u16* __restrict__ qt, u16* __restrict__ kt, u16* __restrict__ vv)
{
    __shared__ QSmem sm;
    const int b = blockIdx.y, n0 = blockIdx.x * 32;
    const int t = threadIdx.x;
    const int lane = t & 63, w = t >> 6;
    const int quad = lane >> 4, c16 = lane & 15;

    // ---- stage x^T bf16: 8 coalesced float4 loads, transpose-pack
    {
        const float* xb = x + (size_t)b * CC * NN + n0;
        const int n4 = (t & 7) * 4;       // n quad 0..28
        const int cr = t >> 3;            // 0..31: c within group of 32
        float4 f[8];
#pragma unroll
        for (int it = 0; it < 8; ++it)
            f[it] = *(const float4*)(xb + (size_t)(it * 32 + cr) * NN + n4);
#pragma unroll
        for (int it = 0; it < 8; ++it) {
            const int c = it * 32 + cr;
            sm.xs[n4 + 0][c] = f2bf(f[it].x);
            sm.xs[n4 + 1][c] = f2bf(f[it].y);
            sm.xs[n4 + 2][c] = f2bf(f[it].z);
            sm.xs[n4 + 3][c] = f2bf(f[it].w);
        }
    }
    __syncthreads();

    // per-rs W row pointers (row = rt*16 + c16 of fused [Wq;Wk;Wv])
    const float* wsrc[5];
#pragma unroll
    for (int rs = 0; rs < 5; ++rs) {
        const int rt = w * 5 + rs;
        wsrc[rs] = (rt < 2) ? &Wq[(rt * 16 + c16) * 256]
                 : (rt < 4) ? &Wk[((rt - 2) * 16 + c16) * 256]
                            : &Wv[((rt - 4) * 16 + c16) * 256];
    }

    f32x4 acc[5][2];
#pragma unroll
    for (int i = 0; i < 5; ++i)
#pragma unroll
        for (int j = 0; j < 2; ++j) acc[i][j] = (f32x4){0.f, 0.f, 0.f, 0.f};

#pragma unroll 1
    for (int k = 0; k < 8; ++k) {
        const int c0 = k * 32;
        bf16x8 wa[5], xb[2];
#pragma unroll
        for (int rs = 0; rs < 5; ++rs) { // direct W load: 8 consecutive f32
            const float4 f0 = *(const float4*)&wsrc[rs][c0 + quad * 8];
            const float4 f1 = *(const float4*)&wsrc[rs][c0 + quad * 8 + 4];
            union { unsigned u[4]; bf16x8 v; } wu;
            wu.u[0] = cvt_pk_bf16(f0.x, f0.y);
            wu.u[1] = cvt_pk_bf16(f0.z, f0.w);
            wu.u[2] = cvt_pk_bf16(f1.x, f1.y);
            wu.u[3] = cvt_pk_bf16(f1.z, f1.w);
            wa[rs] = wu.v;
        }
#pragma unroll
        for (int ns = 0; ns < 2; ++ns) { // B: n-col = lane&15, k=c=quad*8+j
            const short4 a = *(const short4*)&sm.xs[ns * 16 + c16][c0 + quad * 8];
            const short4 b2 = *(const short4*)&sm.xs[ns * 16 + c16][c0 + quad * 8 + 4];
            bf16x8 v;
            v[0] = a.x; v[1] = a.y; v[2] = a.z; v[3] = a.w;
            v[4] = b2.x; v[5] = b2.y; v[6] = b2.z; v[7] = b2.w;
            xb[ns] = v;
        }
#pragma unroll
        for (int rs = 0; rs < 5; ++rs)
#pragma unroll
            for (int ns = 0; ns < 2; ++ns)
                acc[rs][ns] = __builtin_amdgcn_mfma_f32_16x16x32_bf16(
                    wa[rs], xb[ns], acc[rs][ns], 0, 0, 0);
    }

    __syncthreads();   // xs dead; osv may alias it now

    // ---- scatter D + bias into LDS result tiles (bf16)
#pragma unroll
    for (int rs = 0; rs < 5; ++rs) {
#pragma unroll
        for (int r = 0; r < 4; ++r) {
            const int rg = w * 80 + rs * 16 + quad * 4 + r;
            const float bias = (rg < 32) ? bq[rg] : (rg < 64) ? bk[rg - 32] : bv[rg - 64];
#pragma unroll
            for (int ns = 0; ns < 2; ++ns) {
                const int n = ns * 16 + c16;
                const u16 h = f2bf(acc[rs][ns][r] + bias);
                if (rg < 64) sm.osqk[n][rg] = h;
                else         sm.osv[rg - 64][n] = h;
            }
        }
    }
    __syncthreads();

    // ---- coalesced global writes (standard layouts)
    {
        u16* dst = (t >= 128) ? kt : qt;
        const int dof = (t >= 128) ? 32 : 0;
        const int o = (t & 127) * 8;                       // flat in [n][32]
        const int n = o >> 5, d = o & 31;
        const bf16x8 v = *(const bf16x8*)&sm.osqk[n][d + dof];
        *(bf16x8*)&dst[((size_t)b * NN + n0) * CQ + o] = v;
    }
#pragma unroll
    for (int it = 0; it < 4; ++it) {
        const int o = it * 2048 + t * 8;                   // flat in [256][32]
        const int c = o >> 5, n = o & 31;
        const bf16x8 v = *(const bf16x8*)&sm.osv[c][n];
        *(bf16x8*)&vv[((size_t)b * CC + c) * NN + n0 + n] = v;
    }
}

// ---------------------------------------------------------------------------
// Kernel 2: flash attention — RESTORED r3 structure (proven 48.6us, the
// best of 8 rounds; r4-r7 alternatives all lost). m64 / 8 waves (512 thr),
// S split (sm,sh) across waves, P through LDS bf16 swizzled, one barrier
// per step, grid 512 = 2 blocks/CU = 16 waves/CU.
// ONE delta vs r3: P-buffer stride 72 -> 68 u16 (34 dw == 2 mod 32). r4's
// exact conflict count (2^21 = 4 cyc x every PV ds_read_b128) showed the
// 72-stride read pattern pays 4 extra cyc/read; 68 spreads the 16 rows
// across distinct even banks (~2-way, free per HW measurement).
// ---------------------------------------------------------------------------
__global__ __launch_bounds__(512, 4) void attn_kernel(
    const u16* __restrict__ qt, const u16* __restrict__ kt,
    const u16* __restrict__ vv, const float* __restrict__ x,
    const float* __restrict__ gamma_p, float* __restrict__ out)
{
    __shared__ u16 ps16[2][64][68];  // P dbuf, bf16, swizzled (17,408 B)
    __shared__ float lsh[64];        // shared l[m]

    // XCD-aware decode: wg->XCD is round-robin on linear id (id%8).
    const int bid  = blockIdx.x;
    const int xcd  = bid & 7;
    const int slot = bid >> 3;                 // 0..63 within XCD
    const int b    = (xcd << 2) | (slot >> 4); // 4 batches per XCD
    const int m0   = (slot & 15) * 64;

    const int t = threadIdx.x, lane = t & 63, w = t >> 6;  // w 0..7
    const int quad = lane >> 4, c16 = lane & 15;
    const int ch   = c16 >> 3;        // write-side n-block low bit
    const int c7   = c16 & 7;
    const int qkey = (c16 >> 2) & 3;  // read-side swizzle key
    const int sm   = w & 3;           // S m-strip (16 rows)
    const int sh   = w >> 2;          // S n-half (32 cols)
    const int ms0  = w & 3;           // lsum ownership

    // Q A-frag for this wave's S m-strip: Q[m=lane&15][d=quad*8+j]
    const bf16x8 qa = *(const bf16x8*)&qt[((size_t)b * NN + m0 + sm * 16 + c16) * CQ + quad * 8];

    bf16x8 ones;
#pragma unroll
    for (int j = 0; j < 8; ++j) ones[j] = (short)0x3F80;   // bf16 1.0

    f32x4 accO[2][4];                // [cs][ms] of O^T: row=c (c32 strip), col=m
    f32x4 lsum = (f32x4){0.f, 0.f, 0.f, 0.f};   // l for ms0 only
#pragma unroll
    for (int cs = 0; cs < 2; ++cs)
#pragma unroll
        for (int j = 0; j < 4; ++j) accO[cs][j] = (f32x4){0.f, 0.f, 0.f, 0.f};

    const u16* vbase = vv + (size_t)b * CC * NN;   // V[c][n]
    const u16* kbase = kt + (size_t)b * NN * CQ;   // K^T[n][d]

    // pre-issue K frags for step 0 (this wave's n-half)
    bf16x8 kb[2];
#pragma unroll
    for (int s = 0; s < 2; ++s)      // B: n-col = lane&15, k=d=quad*8+j
        kb[s] = *(const bf16x8*)&kbase[(size_t)(sh * 32 + s * 16 + c16) * CQ + quad * 8];

    for (int step = 0; step < 16; ++step) {
        const int nbase = step * 64;
        u16* psb = &ps16[step & 1][0][0];

        // V A-frags for this step (c32 strip; consumed post-barrier:
        // S + exp + barrier wait covers the L2 latency)
        bf16x8 va[2][2];
#pragma unroll
        for (int cs = 0; cs < 2; ++cs)
#pragma unroll
            for (int kc = 0; kc < 2; ++kc)   // A: c-row = lane&15, k=n=quad*8+j
                va[cs][kc] = *(const bf16x8*)&vbase[
                    (size_t)(w * 32 + cs * 16 + c16) * NN + nbase + kc * 32 + quad * 8];

        // ---- S strip [16 m][32 n]: wave (sm, sh) owns a unique piece ----
        f32x4 accS[2];
#pragma unroll
        for (int s = 0; s < 2; ++s)
            accS[s] = __builtin_amdgcn_mfma_f32_16x16x32_bf16(
                qa, kb[s], (f32x4){0.f, 0.f, 0.f, 0.f}, 0, 0, 0);

        // ---- P = exp(S) -> bf16 via cvt_pk, swizzled b16 stores ----
        const int rowb = sm * 16 + quad * 4;
#pragma unroll
        for (int s = 0; s < 2; ++s) {
            const int nb = (sh * 4 + 2 * s + ch) ^ quad;
            u16* pw = &psb[rowb * 68 + nb * 8 + c7];
            const float e0 = __expf(accS[s][0]);
            const float e1 = __expf(accS[s][1]);
            const float e2 = __expf(accS[s][2]);
            const float e3 = __expf(accS[s][3]);
            const unsigned p01 = cvt_pk_bf16(e0, e1);
            const unsigned p23 = cvt_pk_bf16(e2, e3);
            pw[0]   = (u16)p01;
            pw[68]  = (u16)(p01 >> 16);
            pw[136] = (u16)p23;
            pw[204] = (u16)(p23 >> 16);
        }

        // prefetch K frags for next step
        if (step < 15) {
#pragma unroll
            for (int s = 0; s < 2; ++s)
                kb[s] = *(const bf16x8*)&kbase[
                    (size_t)(nbase + 64 + sh * 32 + s * 16 + c16) * CQ + quad * 8];
        }

        __syncthreads();             // ps[cur] visible to all waves

        // ---- PV: O^T[c][m] += V^T[c][n] · P^T[n][m] ; l[ms0] += 1 · P^T ----
#pragma unroll
        for (int msi = 0; msi < 4; ++msi) {
            bf16x8 pb[2];
#pragma unroll
            for (int kc = 0; kc < 2; ++kc)   // direct b128, swizzled addr
                pb[kc] = *(const bf16x8*)&psb[(msi * 16 + c16) * 68
                                              + (4 * kc + (quad ^ qkey)) * 8];
            if (msi == ms0) {
                lsum = __builtin_amdgcn_mfma_f32_16x16x32_bf16(ones, pb[0], lsum, 0, 0, 0);
                lsum = __builtin_amdgcn_mfma_f32_16x16x32_bf16(ones, pb[1], lsum, 0, 0, 0);
            }
#pragma unroll
            for (int cs = 0; cs < 2; ++cs)
#pragma unroll
                for (int kc = 0; kc < 2; ++kc)
                    accO[cs][msi] = __builtin_amdgcn_mfma_f32_16x16x32_bf16(
                        va[cs][kc], pb[kc], accO[cs][msi], 0, 0, 0);
        }
    }

    // ---- share l[m] (each ms owned by waves w&3==ms; sh==0 half writes) ----
    if (sh == 0 && quad == 0) lsh[ms0 * 16 + c16] = lsum[0];
    __syncthreads();

    // ---- epilogue: out = gamma * O / l + x ----
    const float gamma = gamma_p[0];
#pragma unroll
    for (int ms = 0; ms < 4; ++ms) {
        const float inv = gamma / lsh[ms * 16 + c16];
        const int m = m0 + ms * 16 + c16;
#pragma unroll
        for (int cs = 0; cs < 2; ++cs) {
            const int cbase = w * 32 + cs * 16 + quad * 4;
#pragma unroll
            for (int r = 0; r < 4; ++r) {
                const size_t idx = ((size_t)b * CC + cbase + r) * NN + m;
                out[idx] = accO[cs][ms][r] * inv + x[idx];
            }
        }
    }
}

// ---------------------------------------------------------------------------
extern "C" void kernel_launch(void* const* d_in, const int* in_sizes, int n_in,
                              void* d_out, int out_size, void* d_ws, size_t ws_size,
                              hipStream_t stream)
{
    const float* x  = (const float*)d_in[0];
    const float* Wq = (const float*)d_in[1];
    const float* bq = (const float*)d_in[2];
    const float* Wk = (const float*)d_in[3];
    const float* bk = (const float*)d_in[4];
    const float* Wv = (const float*)d_in[5];
    const float* bv = (const float*)d_in[6];
    const float* gm = (const float*)d_in[7];
    float* out = (float*)d_out;

    // workspace (bf16): qt 2MB | kt 2MB | vv 16MB
    u16* qt = (u16*)d_ws;
    u16* kt = qt + (size_t)BB * NN * CQ;
    u16* vv = kt + (size_t)BB * NN * CQ;

    dim3 grid(32, BB);
    qkv_kernel<<<grid, 256, 0, stream>>>(x, Wq, Wk, Wv, bq, bk, bv, qt, kt, vv);
    attn_kernel<<<512, 512, 0, stream>>>(qt, kt, vv, x, gm, out);
}

// Round 10
// 178.073 us; speedup vs baseline: 1.1221x; 1.1221x over previous
//
#include <hip/hip_runtime.h>
#include <math.h>

#define BB 32
#define CC 256
#define CQ 32      // C/8
#define NN 1024    // H*W

typedef short bf16x8 __attribute__((ext_vector_type(8)));
typedef float f32x4  __attribute__((ext_vector_type(4)));
typedef unsigned short u16;

// fp32 -> bf16 RNE
__device__ __forceinline__ u16 f2bf(float f) {
    unsigned u = __float_as_uint(f);
    u = (u + 0x7FFFu + ((u >> 16) & 1u)) >> 16;
    return (u16)u;
}

// pack two fp32 -> two bf16 in one u32 (single VALU op)
__device__ __forceinline__ unsigned cvt_pk_bf16(float lo, float hi) {
    unsigned r;
    asm("v_cvt_pk_bf16_f32 %0, %1, %2" : "=v"(r) : "v"(lo), "v"(hi));
    return r;
}

// ---------------------------------------------------------------------------
// Kernel 0: pack fused W = [Wq(32); Wk(32); Wv(256)] into MFMA A-frag order.
// RESTORED (r8's W-direct qkv cost ~20us: global loads in the MFMA loop).
// ---------------------------------------------------------------------------
__global__ void wpack_kernel(const float* __restrict__ Wq,
                             const float* __restrict__ Wk,
                             const float* __restrict__ Wv,
                             u16* __restrict__ wfrag)
{
    const int o = blockIdx.x * 256 + threadIdx.x;     // 0 .. 81919
    const int j    = o & 7;
    const int lane = (o >> 3) & 63;
    const int kc   = (o >> 9) & 7;
    const int rt   = o >> 12;                         // 0..19
    const int row  = rt * 16 + (lane & 15);
    const int col  = kc * 32 + (lane >> 4) * 8 + j;
    const float v = (row < 32) ? Wq[row * 256 + col]
                  : (row < 64) ? Wk[(row - 32) * 256 + col]
                               : Wv[(row - 64) * 256 + col];
    wfrag[o] = f2bf(v);
}

// ---------------------------------------------------------------------------
// Kernel 1: QKV projection — r3/r4 version verbatim (best measured residue,
// 101us total minus attn). grid(32 n-tiles, 32 b), 256 thr.
// ---------------------------------------------------------------------------
struct QSmem {
    union {
        u16 xs[32][268];     // x^T tile [n][c] bf16, stride 268 (bank-spread)
        u16 osv[CC][40];     // v result [c][n]
    };
    u16 osqk[32][72];        // q|k result [n][d], d 0..31 = q, 32..63 = k
};

__global__ __launch_bounds__(256, 4) void qkv_kernel(
    const float* __restrict__ x, const u16* __restrict__ wfrag,
    const float* __restrict__ bq, const float* __restrict__ bk,
    const float* __restrict__ bv,
    u16* __restrict__ qt, u16* __restrict__ kt, u16* __restrict__ vv)
{
    __shared__ QSmem sm;
    const int b = blockIdx.y, n0 = blockIdx.x * 32;
    const int t = threadIdx.x;
    const int lane = t & 63, w = t >> 6;
    const int quad = lane >> 4, c16 = lane & 15;

    // ---- stage x^T bf16: 8 coalesced float4 loads, transpose-pack
    {
        const float* xb = x + (size_t)b * CC * NN + n0;
        const int n4 = (t & 7) * 4;       // n quad 0..28
        const int cr = t >> 3;            // 0..31: c within group of 32
        float4 f[8];
#pragma unroll
        for (int it = 0; it < 8; ++it)
            f[it] = *(const float4*)(xb + (size_t)(it * 32 + cr) * NN + n4);
#pragma unroll
        for (int it = 0; it < 8; ++it) {
            const int c = it * 32 + cr;
            sm.xs[n4 + 0][c] = f2bf(f[it].x);
            sm.xs[n4 + 1][c] = f2bf(f[it].y);
            sm.xs[n4 + 2][c] = f2bf(f[it].z);
            sm.xs[n4 + 3][c] = f2bf(f[it].w);
        }
    }
    __syncthreads();

    f32x4 acc[5][2];
#pragma unroll
    for (int i = 0; i < 5; ++i)
#pragma unroll
        for (int j = 0; j < 2; ++j) acc[i][j] = (f32x4){0.f, 0.f, 0.f, 0.f};

#pragma unroll 2
    for (int k = 0; k < 8; ++k) {
        const int c0 = k * 32;
        bf16x8 wa[5], xb[2];
#pragma unroll
        for (int rs = 0; rs < 5; ++rs)   // swizzled W: 16 B/lane contiguous
            wa[rs] = *(const bf16x8*)&wfrag[(size_t)(((w * 5 + rs) * 8 + k) * 64 + lane) * 8];
#pragma unroll
        for (int ns = 0; ns < 2; ++ns) { // B: n-col = lane&15, k=c=quad*8+j
            const short4 a = *(const short4*)&sm.xs[ns * 16 + c16][c0 + quad * 8];
            const short4 b2 = *(const short4*)&sm.xs[ns * 16 + c16][c0 + quad * 8 + 4];
            bf16x8 v;
            v[0] = a.x; v[1] = a.y; v[2] = a.z; v[3] = a.w;
            v[4] = b2.x; v[5] = b2.y; v[6] = b2.z; v[7] = b2.w;
            xb[ns] = v;
        }
#pragma unroll
        for (int rs = 0; rs < 5; ++rs)
#pragma unroll
            for (int ns = 0; ns < 2; ++ns)
                acc[rs][ns] = __builtin_amdgcn_mfma_f32_16x16x32_bf16(
                    wa[rs], xb[ns], acc[rs][ns], 0, 0, 0);
    }

    __syncthreads();   // xs dead; osv may alias it now

    // ---- scatter D + bias into LDS result tiles (bf16)
#pragma unroll
    for (int rs = 0; rs < 5; ++rs) {
#pragma unroll
        for (int r = 0; r < 4; ++r) {
            const int rg = w * 80 + rs * 16 + quad * 4 + r;
            const float bias = (rg < 32) ? bq[rg] : (rg < 64) ? bk[rg - 32] : bv[rg - 64];
#pragma unroll
            for (int ns = 0; ns < 2; ++ns) {
                const int n = ns * 16 + c16;
                const u16 h = f2bf(acc[rs][ns][r] + bias);
                if (rg < 64) sm.osqk[n][rg] = h;
                else         sm.osv[rg - 64][n] = h;
            }
        }
    }
    __syncthreads();

    // ---- coalesced global writes (standard layouts)
    {
        u16* dst = (t >= 128) ? kt : qt;
        const int dof = (t >= 128) ? 32 : 0;
        const int o = (t & 127) * 8;                       // flat in [n][32]
        const int n = o >> 5, d = o & 31;
        const bf16x8 v = *(const bf16x8*)&sm.osqk[n][d + dof];
        *(bf16x8*)&dst[((size_t)b * NN + n0) * CQ + o] = v;
    }
#pragma unroll
    for (int it = 0; it < 4; ++it) {
        const int o = it * 2048 + t * 8;                   // flat in [256][32]
        const int c = o >> 5, n = o & 31;
        const bf16x8 v = *(const bf16x8*)&sm.osv[c][n];
        *(bf16x8*)&vv[((size_t)b * CC + c) * NN + n0 + n] = v;
    }
}

// ---------------------------------------------------------------------------
// Kernel 2: flash attention — r3 base (stride 72, 16-B aligned; r8's stride
// 68 broke b128 alignment: conflicts 0 but +56% time). ONE change vs r3:
// PV re-geometry. Wave = (mh = m-half, cq = c-quarter): owns m32 x c64 of O.
// Post-barrier critical path: 4 ds_read_b128 (was 8); P-read LDS traffic
// per CU halves (128->64 KB/step). accO MFMA count unchanged (16/wave).
// V loads duplicate x2 across mh-pairs (+18 B/cy prefetched L2 - trivial).
// Store side, swizzle, barriers: byte-identical to r3.
// ---------------------------------------------------------------------------
__global__ __launch_bounds__(512, 4) void attn_kernel(
    const u16* __restrict__ qt, const u16* __restrict__ kt,
    const u16* __restrict__ vv, const float* __restrict__ x,
    const float* __restrict__ gamma_p, float* __restrict__ out)
{
    __shared__ u16 ps16[2][64][72];  // P dbuf, bf16, swizzled (18,432 B)
    __shared__ float lsh[64];        // shared l[m]

    // XCD-aware decode: wg->XCD is round-robin on linear id (id%8).
    const int bid  = blockIdx.x;
    const int xcd  = bid & 7;
    const int slot = bid >> 3;                 // 0..63 within XCD
    const int b    = (xcd << 2) | (slot >> 4); // 4 batches per XCD
    const int m0   = (slot & 15) * 64;

    const int t = threadIdx.x, lane = t & 63, w = t >> 6;  // w 0..7
    const int quad = lane >> 4, c16 = lane & 15;
    const int ch   = c16 >> 3;        // write-side n-block low bit
    const int c7   = c16 & 7;
    const int qkey = (c16 >> 2) & 3;  // read-side swizzle key
    const int mh   = w & 1;           // PV m-half (32 rows)
    const int cq   = w >> 1;          // PV c-quarter (64 channels)
    const int sm   = mh * 2 + (cq & 1);  // S m-strip (16 rows)
    const int sh   = cq >> 1;            // S n-half (32 cols)
    const int c0   = cq * 64;

    // Q A-frag for this wave's S m-strip: Q[m=lane&15][d=quad*8+j]
    const bf16x8 qa = *(const bf16x8*)&qt[((size_t)b * NN + m0 + sm * 16 + c16) * CQ + quad * 8];

    bf16x8 ones;
#pragma unroll
    for (int j = 0; j < 8; ++j) ones[j] = (short)0x3F80;   // bf16 1.0

    f32x4 accO[4][2];                // [cs][mi] of O^T: row=c (c64), col=m (m32)
    f32x4 lsum[2];                   // cq==0 waves accumulate l for their mh
#pragma unroll
    for (int mi = 0; mi < 2; ++mi) {
        lsum[mi] = (f32x4){0.f, 0.f, 0.f, 0.f};
#pragma unroll
        for (int cs = 0; cs < 4; ++cs) accO[cs][mi] = (f32x4){0.f, 0.f, 0.f, 0.f};
    }

    const u16* vbase = vv + (size_t)b * CC * NN;   // V[c][n]
    const u16* kbase = kt + (size_t)b * NN * CQ;   // K^T[n][d]

    // pre-issue K frags for step 0 (this wave's n-half)
    bf16x8 kb[2];
#pragma unroll
    for (int s = 0; s < 2; ++s)      // B: n-col = lane&15, k=d=quad*8+j
        kb[s] = *(const bf16x8*)&kbase[(size_t)(sh * 32 + s * 16 + c16) * CQ + quad * 8];

    for (int step = 0; step < 16; ++step) {
        const int nbase = step * 64;
        u16* psb = &ps16[step & 1][0][0];

        // V A-frags for this step (c64 strip; consumed post-barrier:
        // S + exp + barrier wait covers the L2 latency)
        bf16x8 va[4][2];
#pragma unroll
        for (int cs = 0; cs < 4; ++cs)
#pragma unroll
            for (int kc = 0; kc < 2; ++kc)   // A: c-row = lane&15, k=n=quad*8+j
                va[cs][kc] = *(const bf16x8*)&vbase[
                    (size_t)(c0 + cs * 16 + c16) * NN + nbase + kc * 32 + quad * 8];

        // ---- S strip [16 m][32 n]: wave (sm, sh) owns a unique piece ----
        f32x4 accS[2];
#pragma unroll
        for (int s = 0; s < 2; ++s)
            accS[s] = __builtin_amdgcn_mfma_f32_16x16x32_bf16(
                qa, kb[s], (f32x4){0.f, 0.f, 0.f, 0.f}, 0, 0, 0);

        // ---- P = exp(S) -> bf16 via cvt_pk, swizzled b16 stores ----
        const int rowb = sm * 16 + quad * 4;
#pragma unroll
        for (int s = 0; s < 2; ++s) {
            const int nb = (sh * 4 + 2 * s + ch) ^ quad;
            u16* pw = &psb[rowb * 72 + nb * 8 + c7];
            const float e0 = __expf(accS[s][0]);
            const float e1 = __expf(accS[s][1]);
            const float e2 = __expf(accS[s][2]);
            const float e3 = __expf(accS[s][3]);
            const unsigned p01 = cvt_pk_bf16(e0, e1);
            const unsigned p23 = cvt_pk_bf16(e2, e3);
            pw[0]   = (u16)p01;
            pw[72]  = (u16)(p01 >> 16);
            pw[144] = (u16)p23;
            pw[216] = (u16)(p23 >> 16);
        }

        // prefetch K frags for next step
        if (step < 15) {
#pragma unroll
            for (int s = 0; s < 2; ++s)
                kb[s] = *(const bf16x8*)&kbase[
                    (size_t)(nbase + 64 + sh * 32 + s * 16 + c16) * CQ + quad * 8];
        }

        __syncthreads();             // ps[cur] visible to all waves

        // ---- PV: O^T[c][m] += V^T[c][n] · P^T[n][m] ----
#pragma unroll
        for (int mi = 0; mi < 2; ++mi) {
            const int msi = mh * 2 + mi;
            bf16x8 pb[2];
#pragma unroll
            for (int kc = 0; kc < 2; ++kc)   // direct b128, swizzled addr
                pb[kc] = *(const bf16x8*)&psb[(msi * 16 + c16) * 72
                                              + (4 * kc + (quad ^ qkey)) * 8];
            if (cq == 0) {                   // l owner for this mh
                lsum[mi] = __builtin_amdgcn_mfma_f32_16x16x32_bf16(ones, pb[0], lsum[mi], 0, 0, 0);
                lsum[mi] = __builtin_amdgcn_mfma_f32_16x16x32_bf16(ones, pb[1], lsum[mi], 0, 0, 0);
            }
#pragma unroll
            for (int cs = 0; cs < 4; ++cs)
#pragma unroll
                for (int kc = 0; kc < 2; ++kc)
                    accO[cs][mi] = __builtin_amdgcn_mfma_f32_16x16x32_bf16(
                        va[cs][kc], pb[kc], accO[cs][mi], 0, 0, 0);
        }
    }

    // ---- share l[m] (cq==0 wave of each mh owns rows mh*32..mh*32+31) ----
    if (cq == 0 && quad == 0) {
        lsh[(mh * 2 + 0) * 16 + c16] = lsum[0][0];
        lsh[(mh * 2 + 1) * 16 + c16] = lsum[1][0];
    }
    __syncthreads();

    // ---- epilogue: out = gamma * O / l + x ----
    const float gamma = gamma_p[0];
#pragma unroll
    for (int mi = 0; mi < 2; ++mi) {
        const int msi = mh * 2 + mi;
        const float inv = gamma / lsh[msi * 16 + c16];
        const int m = m0 + msi * 16 + c16;
#pragma unroll
        for (int cs = 0; cs < 4; ++cs) {
            const int cbase = c0 + cs * 16 + quad * 4;
#pragma unroll
            for (int r = 0; r < 4; ++r) {
                const size_t idx = ((size_t)b * CC + cbase + r) * NN + m;
                out[idx] = accO[cs][mi][r] * inv + x[idx];
            }
        }
    }
}

// ---------------------------------------------------------------------------
extern "C" void kernel_launch(void* const* d_in, const int* in_sizes, int n_in,
                              void* d_out, int out_size, void* d_ws, size_t ws_size,
                              hipStream_t stream)
{
    const float* x  = (const float*)d_in[0];
    const float* Wq = (const float*)d_in[1];
    const float* bq = (const float*)d_in[2];
    const float* Wk = (const float*)d_in[3];
    const float* bk = (const float*)d_in[4];
    const float* Wv = (const float*)d_in[5];
    const float* bv = (const float*)d_in[6];
    const float* gm = (const float*)d_in[7];
    float* out = (float*)d_out;

    // workspace (bf16): qt 2MB | kt 2MB | vv 16MB | wfrag 160KB
    u16* qt    = (u16*)d_ws;
    u16* kt    = qt + (size_t)BB * NN * CQ;
    u16* vv    = kt + (size_t)BB * NN * CQ;
    u16* wfrag = vv + (size_t)BB * CC * NN;

    wpack_kernel<<<320, 256, 0, stream>>>(Wq, Wk, Wv, wfrag);
    dim3 grid(32, BB);
    qkv_kernel<<<grid, 256, 0, stream>>>(x, wfrag, bq, bk, bv, qt, kt, vv);
    attn_kernel<<<512, 512, 0, stream>>>(qt, kt, vv, x, gm, out);
}